// Round 1
// baseline (3878.829 us; speedup 1.0000x reference)
//
#include <hip/hip_runtime.h>
#include <hip/hip_bf16.h>

#define B_  512
#define T_  256
#define E_  256
#define H_  512
#define V_  1000
#define CH  16   // timesteps per persistent chunk / out_proj chunk

typedef __attribute__((ext_vector_type(8))) short short8;
typedef __attribute__((ext_vector_type(4))) float f32x4;
typedef __hip_bfloat16 bf16;

#define MFMA16(a, b, c) __builtin_amdgcn_mfma_f32_16x16x32_bf16((a), (b), (c), 0, 0, 0)

// ---------------------------------------------------------------------------
// fp32 -> bf16 pre-conversion (weights/embedding), 8 elems/thread
// ---------------------------------------------------------------------------
__global__ void f32_to_bf16_kernel(const float* __restrict__ src,
                                   bf16* __restrict__ dst, int n8) {
  int i = blockIdx.x * blockDim.x + threadIdx.x;
  if (i >= n8) return;
  const float4* s4 = (const float4*)src;
  float4 a = s4[2 * i], b = s4[2 * i + 1];
  bf16 tmp[8] = {__float2bfloat16(a.x), __float2bfloat16(a.y),
                 __float2bfloat16(a.z), __float2bfloat16(a.w),
                 __float2bfloat16(b.x), __float2bfloat16(b.y),
                 __float2bfloat16(b.z), __float2bfloat16(b.w)};
  *(int4*)(dst + 8 * i) = *(const int4*)tmp;
}

// ---------------------------------------------------------------------------
// One-time: embProjB[v][n] = emb[v] @ W_ih^T[n] + b_ih[n] + b_hh[n]   (f32)
// The per-step x-contribution to the gates is a pure function of the char id.
// grid (16, 32): x -> 64-row vocab block (1024 padded), y -> 64 gate cols.
// ---------------------------------------------------------------------------
__global__ __launch_bounds__(256) void embproj_kernel(
    const bf16* __restrict__ emb, const bf16* __restrict__ Wih,
    const float* __restrict__ b_ih, const float* __restrict__ b_hh,
    float* __restrict__ embProjB)
{
  __shared__ short As[64][40];
  __shared__ short Bs[64][40];
  const int tid  = threadIdx.x;
  const int wave = tid >> 6, lane = tid & 63;
  const int q = lane >> 4, col = lane & 15;
  const int m0 = blockIdx.x * 64;
  const int n0 = blockIdx.y * 64;
  const int sr  = tid >> 2, skc = (tid & 3) * 8;
  const int mr  = wave * 16 + col;
  const int ko  = q * 8;
  int arow = m0 + sr; if (arow > V_ - 1) arow = V_ - 1;

  f32x4 acc0 = {0.f,0.f,0.f,0.f}, acc1 = acc0, acc2 = acc0, acc3 = acc0;
  for (int k0 = 0; k0 < E_; k0 += 32) {
    *(int4*)&As[sr][skc] = *(const int4*)((const short*)emb + (size_t)arow * E_ + k0 + skc);
    *(int4*)&Bs[sr][skc] = *(const int4*)((const short*)Wih + (size_t)(n0 + sr) * E_ + k0 + skc);
    __syncthreads();
    short8 a  = *(const short8*)&As[mr][ko];
    short8 b0 = *(const short8*)&Bs[ 0 + col][ko];
    short8 b1 = *(const short8*)&Bs[16 + col][ko];
    short8 b2 = *(const short8*)&Bs[32 + col][ko];
    short8 b3 = *(const short8*)&Bs[48 + col][ko];
    acc0 = MFMA16(a, b0, acc0);
    acc1 = MFMA16(a, b1, acc1);
    acc2 = MFMA16(a, b2, acc2);
    acc3 = MFMA16(a, b3, acc3);
    __syncthreads();
  }
#pragma unroll
  for (int r = 0; r < 4; r++) {
    int m = m0 + wave * 16 + q * 4 + r;
    if (m < V_) {
      float* dst = embProjB + (size_t)m * 2048;
      int n = n0 + col;
      dst[n +  0] = acc0[r] + b_ih[n +  0] + b_hh[n +  0];
      dst[n + 16] = acc1[r] + b_ih[n + 16] + b_hh[n + 16];
      dst[n + 32] = acc2[r] + b_ih[n + 32] + b_hh[n + 32];
      dst[n + 48] = acc3[r] + b_ih[n + 48] + b_hh[n + 48];
    }
  }
}

// ---------------------------------------------------------------------------
// Persistent recurrence chunk kernel: CH timesteps per launch, 256 blocks.
// bid&7 -> batch group mb (64 rows, XCD-pinned by %8 round-robin heuristic),
// bid>>3 -> hidden-col group jb (16 cols => 64 gate rows held in LDS all chunk).
// Cross-block h exchange within a 32-block group via release/acquire flags.
// c-state lives in registers for the whole chunk. h ring slot == step index s.
// ---------------------------------------------------------------------------
__global__ __launch_bounds__(256) void recur_kernel(
    const int* __restrict__ gt,
    const bf16* __restrict__ Whh,        // [2048][512] bf16
    const float* __restrict__ embProjB,  // [1000][2048] f32 (biases folded)
    const bf16* __restrict__ hprev0,     // h at t0-1 (zeros for t0==0)
    bf16* __restrict__ h1buf,            // [CH][B][H] bf16 ring
    float* __restrict__ c_state,         // [B][H] f32
    int* __restrict__ flags,             // [CH][8][32] int
    int t0)
{
  __shared__ short Wl[64][520];   // 64 gate rows x 512 k, +8 pad
  __shared__ int chars[64];

  const int tid  = threadIdx.x;
  const int wave = tid >> 6, lane = tid & 63;
  const int q = lane >> 4, col = lane & 15;
  const int bid = blockIdx.x;
  const int mb = bid & 7, jb = bid >> 3;
  const int m0 = mb * 64, j0 = jb * 16;
  const int chunkv = (t0 >> 4) + 1;

  // stage this block's W_hh slice into LDS once per chunk
  for (int cch = tid; cch < 64 * 64; cch += 256) {
    int r = cch >> 6, kc = (cch & 63) * 8;
    int gr = (r >> 4) * H_ + j0 + (r & 15);
    *(int4*)&Wl[r][kc] = *(const int4*)((const short*)Whh + (size_t)gr * H_ + kc);
  }

  const int mrow = m0 + wave * 16 + q * 4;   // + r for C-rows of this lane
  const int arow = m0 + wave * 16 + col;     // A-row this lane loads

  float creg[4];
#pragma unroll
  for (int r = 0; r < 4; r++)
    creg[r] = c_state[(size_t)(mrow + r) * H_ + j0 + col];

  for (int s = 0; s < CH; s++) {
    const int t = t0 + s;
    if (tid < 64) chars[tid] = (t == 0) ? 0 : gt[(m0 + tid) * T_ + (t - 1)];
    if (s > 0 && tid < 32) {
      int* fl = flags + (((s - 1) * 8 + mb) << 5) + tid;
      while (__hip_atomic_load(fl, __ATOMIC_ACQUIRE, __HIP_MEMORY_SCOPE_AGENT) != chunkv) {}
    }
    __syncthreads();   // chars + W (s==0) ready; group h(s-1) visible

    const bf16* hp = (s == 0) ? hprev0 : (h1buf + (size_t)(s - 1) * B_ * H_);

    // x-contribution gather (off critical path: consumed after K-loop)
    float ex[4][4];
#pragma unroll
    for (int r = 0; r < 4; r++) {
      const float* ep = embProjB + (size_t)chars[wave * 16 + q * 4 + r] * 2048 + j0 + col;
#pragma unroll
      for (int g = 0; g < 4; g++) ex[g][r] = ep[g * H_];
    }

    f32x4 acc[4];
#pragma unroll
    for (int g = 0; g < 4; g++) acc[g] = (f32x4){0.f, 0.f, 0.f, 0.f};

    const short* abase = (const short*)hp + (size_t)arow * H_;
#pragma unroll
    for (int k0 = 0; k0 < H_; k0 += 32) {
      short8 a  = *(const short8*)(abase + k0 + q * 8);
      short8 b0 = *(const short8*)&Wl[ 0 + col][k0 + q * 8];
      short8 b1 = *(const short8*)&Wl[16 + col][k0 + q * 8];
      short8 b2 = *(const short8*)&Wl[32 + col][k0 + q * 8];
      short8 b3 = *(const short8*)&Wl[48 + col][k0 + q * 8];
      acc[0] = MFMA16(a, b0, acc[0]);
      acc[1] = MFMA16(a, b1, acc[1]);
      acc[2] = MFMA16(a, b2, acc[2]);
      acc[3] = MFMA16(a, b3, acc[3]);
    }

    // fused LSTM cell update; h -> ring slot s
    bf16* ho = h1buf + (size_t)s * B_ * H_;
#pragma unroll
    for (int r = 0; r < 4; r++) {
      float iv = 1.f / (1.f + __expf(-(acc[0][r] + ex[0][r])));
      float fv = 1.f / (1.f + __expf(-(acc[1][r] + ex[1][r])));
      float gv = tanhf(acc[2][r] + ex[2][r]);
      float ov = 1.f / (1.f + __expf(-(acc[3][r] + ex[3][r])));
      float cN = fv * creg[r] + iv * gv;
      creg[r] = cN;
      ho[(size_t)(mrow + r) * H_ + j0 + col] = __float2bfloat16(ov * tanhf(cN));
    }

    __syncthreads();   // drain all threads' h stores (vmcnt(0) before barrier)
    if (tid == 0)
      __hip_atomic_store(flags + ((s * 8 + mb) << 5) + jb, chunkv,
                         __ATOMIC_RELEASE, __HIP_MEMORY_SCOPE_AGENT);
  }

#pragma unroll
  for (int r = 0; r < 4; r++)
    c_state[(size_t)(mrow + r) * H_ + j0 + col] = creg[r];
}

// ---------------------------------------------------------------------------
// Deferred output projection + log_softmax over a CH-step chunk of h1.
// grid 16*CH: blockIdx >> 4 = step-in-chunk, (blockIdx & 15)*32 = batch base.
// ---------------------------------------------------------------------------
__global__ __launch_bounds__(256) void out_proj_kernel(
    const bf16* __restrict__ h1buf,   // [CH][B][H]
    const bf16* __restrict__ Wout,    // [V][H] bf16 (pre-converted)
    const float* __restrict__ bout,   // [V] fp32
    float* __restrict__ out,          // [B][T][V] fp32
    int t0)
{
  __shared__ short Hs[32][520];
  __shared__ float red[4][32];
  __shared__ float rowM[32];
  __shared__ float rowS[32];

  const int tid  = threadIdx.x;
  const int wave = tid >> 6, lane = tid & 63;
  const int q = lane >> 4, col = lane & 15;
  const int s  = blockIdx.x >> 4;
  const int b0 = (blockIdx.x & 15) * 32;

  const short* hrow = (const short*)h1buf + ((size_t)s * B_ + b0) * H_;
  for (int c = tid; c < 2048; c += 256) {
    int r = c >> 6, kc = (c & 63) << 3;
    *(int4*)&Hs[r][kc] = *(const int4*)&hrow[r * H_ + kc];
  }
  __syncthreads();

  f32x4 acc[2][16];
#pragma unroll
  for (int mt = 0; mt < 2; mt++)
#pragma unroll
    for (int u = 0; u < 16; u++) acc[mt][u] = (f32x4){0.f, 0.f, 0.f, 0.f};

  const short* WS = (const short*)Wout;
  for (int k0 = 0; k0 < H_; k0 += 32) {
    short8 a0 = *(const short8*)&Hs[col][k0 + q * 8];
    short8 a1 = *(const short8*)&Hs[16 + col][k0 + q * 8];
#pragma unroll
    for (int u = 0; u < 16; u++) {
      int nt = wave + 4 * u;
      if (nt < 63) {
        int v = nt * 16 + col;
        int vc = v < V_ ? v : (V_ - 1);
        short8 bfr = *(const short8*)&WS[(size_t)vc * H_ + k0 + q * 8];
        acc[0][u] = MFMA16(a0, bfr, acc[0][u]);
        acc[1][u] = MFMA16(a1, bfr, acc[1][u]);
      }
    }
  }

  float bo[16];
  bool  val[16];
#pragma unroll
  for (int u = 0; u < 16; u++) {
    int nt = wave + 4 * u;
    int v = nt * 16 + col;
    val[u] = (nt < 63) && (v < V_);
    bo[u] = val[u] ? bout[v] : 0.f;
  }

  float mymax[2][4];
#pragma unroll
  for (int mt = 0; mt < 2; mt++)
#pragma unroll
    for (int r = 0; r < 4; r++) mymax[mt][r] = -1e30f;
#pragma unroll
  for (int mt = 0; mt < 2; mt++)
#pragma unroll
    for (int u = 0; u < 16; u++)
      if (val[u]) {
#pragma unroll
        for (int r = 0; r < 4; r++)
          mymax[mt][r] = fmaxf(mymax[mt][r], acc[mt][u][r] + bo[u]);
      }
#pragma unroll
  for (int d = 1; d < 16; d <<= 1)
#pragma unroll
    for (int mt = 0; mt < 2; mt++)
#pragma unroll
      for (int r = 0; r < 4; r++)
        mymax[mt][r] = fmaxf(mymax[mt][r], __shfl_xor(mymax[mt][r], d, 64));
  if (col == 0)
#pragma unroll
    for (int mt = 0; mt < 2; mt++)
#pragma unroll
      for (int r = 0; r < 4; r++)
        red[wave][mt * 16 + q * 4 + r] = mymax[mt][r];
  __syncthreads();
  if (tid < 32)
    rowM[tid] = fmaxf(fmaxf(red[0][tid], red[1][tid]),
                      fmaxf(red[2][tid], red[3][tid]));
  __syncthreads();

  float mysum[2][4] = {{0.f,0.f,0.f,0.f},{0.f,0.f,0.f,0.f}};
#pragma unroll
  for (int mt = 0; mt < 2; mt++)
#pragma unroll
    for (int r = 0; r < 4; r++) {
      float rm = rowM[mt * 16 + q * 4 + r];
#pragma unroll
      for (int u = 0; u < 16; u++)
        if (val[u]) mysum[mt][r] += __expf(acc[mt][u][r] + bo[u] - rm);
    }
#pragma unroll
  for (int d = 1; d < 16; d <<= 1)
#pragma unroll
    for (int mt = 0; mt < 2; mt++)
#pragma unroll
      for (int r = 0; r < 4; r++)
        mysum[mt][r] += __shfl_xor(mysum[mt][r], d, 64);
  if (col == 0)
#pragma unroll
    for (int mt = 0; mt < 2; mt++)
#pragma unroll
      for (int r = 0; r < 4; r++)
        red[wave][mt * 16 + q * 4 + r] = mysum[mt][r];
  __syncthreads();
  if (tid < 32)
    rowS[tid] = __logf(red[0][tid] + red[1][tid] + red[2][tid] + red[3][tid]);
  __syncthreads();

#pragma unroll
  for (int mt = 0; mt < 2; mt++)
#pragma unroll
    for (int r = 0; r < 4; r++) {
      int m = mt * 16 + q * 4 + r;
      float corr = rowM[m] + rowS[m];
      size_t base = ((size_t)(b0 + m) * T_ + (t0 + s)) * V_;
#pragma unroll
      for (int u = 0; u < 16; u++)
        if (val[u]) {
          int v = (wave + 4 * u) * 16 + col;
          out[base + v] = acc[mt][u][r] + bo[u] - corr;
        }
    }
}

// ---------------------------------------------------------------------------
extern "C" void kernel_launch(void* const* d_in, const int* in_sizes, int n_in,
                              void* d_out, int out_size, void* d_ws, size_t ws_size,
                              hipStream_t stream) {
  (void)in_sizes; (void)n_in; (void)out_size; (void)ws_size;
  const int*   gt     = (const int*)d_in[1];
  const float* emb_f  = (const float*)d_in[2];
  // layer 0 weights d_in[3..6] dead code; listener_output d_in[0] unused by ref
  const float* Wih_f  = (const float*)d_in[7];
  const float* Whh_f  = (const float*)d_in[8];
  const float* b_ih1  = (const float*)d_in[9];
  const float* b_hh1  = (const float*)d_in[10];
  const float* Wout_f = (const float*)d_in[11];
  const float* bout   = (const float*)d_in[12];
  float* out = (float*)d_out;

  // ws layout (16B-aligned sections):
  //   c_state f32 [B][H]           1,048,576 B @ 0
  //   hinit   bf16 [B][H] zeros      524,288 B @ 1,048,576
  //   h1buf   bf16 [CH][B][H]      8,388,608 B @ 1,572,864
  //   emb_bf  bf16 [V][E]            512,000 B @ 9,961,472
  //   Wih_bf  bf16 [2048][256]     1,048,576 B @ 10,473,472
  //   Whh_bf  bf16 [2048][512]     2,097,152 B @ 11,522,048
  //   Wout_bf bf16 [1000][512]     1,024,000 B @ 13,619,200
  //   embProjB f32 [1000][2048]    8,192,000 B @ 14,643,200
  //   flags   int [CH][8][32]         16,384 B @ 22,835,200   (total ~21.8 MB)
  char* ws = (char*)d_ws;
  float* c_state = (float*)ws;
  bf16*  hinit   = (bf16*)(ws + 1048576);
  bf16*  h1buf   = (bf16*)(ws + 1572864);
  bf16*  emb_bf  = (bf16*)(ws + 9961472);
  bf16*  Wih_bf  = (bf16*)(ws + 10473472);
  bf16*  Whh_bf  = (bf16*)(ws + 11522048);
  bf16*  Wout_bf = (bf16*)(ws + 13619200);
  float* embP    = (float*)(ws + 14643200);
  int*   flags   = (int*)(ws + 22835200);

  hipMemsetAsync(d_ws, 0, 1572864, stream);   // zero c_state + hinit
  hipMemsetAsync(flags, 0, 16384, stream);    // zero sync flags

  f32_to_bf16_kernel<<<(V_ * E_ / 8 + 255) / 256, 256, 0, stream>>>(emb_f, emb_bf, V_ * E_ / 8);
  f32_to_bf16_kernel<<<(4 * H_ * E_ / 8 + 255) / 256, 256, 0, stream>>>(Wih_f, Wih_bf, 4 * H_ * E_ / 8);
  f32_to_bf16_kernel<<<(4 * H_ * H_ / 8 + 255) / 256, 256, 0, stream>>>(Whh_f, Whh_bf, 4 * H_ * H_ / 8);
  f32_to_bf16_kernel<<<(V_ * H_ / 8 + 255) / 256, 256, 0, stream>>>(Wout_f, Wout_bf, V_ * H_ / 8);

  embproj_kernel<<<dim3(16, 32), 256, 0, stream>>>(emb_bf, Wih_bf, b_ih1, b_hh1, embP);

  for (int chunk = 0; chunk < T_ / CH; chunk++) {
    int t0 = chunk * CH;
    const bf16* hp0 = (chunk == 0) ? hinit : h1buf + (size_t)(CH - 1) * B_ * H_;
    recur_kernel<<<256, 256, 0, stream>>>(gt, Whh_bf, embP, hp0, h1buf, c_state,
                                          flags, t0);
    out_proj_kernel<<<16 * CH, 256, 0, stream>>>(h1buf, Wout_bf, bout, out, t0);
  }
}